// Round 3
// baseline (1549.767 us; speedup 1.0000x reference)
//
#include <hip/hip_runtime.h>
#include <hip/hip_bf16.h>

#define NUM_TOK 8192
#define HID 1024
#define INT_DIM 4096
#define NEXP 8
#define NSLOT 16384  /* NUM_TOK * TOP_K */
#define BM 128
#define BK 32
#define BUFE (128 * BK)   /* ushorts per LDS buffer */

typedef __bf16 bf16x8 __attribute__((ext_vector_type(8)));
typedef float f32x4 __attribute__((ext_vector_type(4)));

typedef const __attribute__((address_space(1))) unsigned int* gas_t;
typedef __attribute__((address_space(3))) unsigned int* las_t;

__device__ __forceinline__ void gl_lds16(const unsigned short* g, unsigned short* l) {
    __builtin_amdgcn_global_load_lds((gas_t)g, (las_t)l, 16, 0, 0);
}

__device__ __forceinline__ unsigned short f2bf(float f) {
    unsigned int x = __builtin_bit_cast(unsigned int, f);
    x += 0x7fffu + ((x >> 16) & 1u);   // RNE
    return (unsigned short)(x >> 16);
}

// ---------------- fp32 -> bf16 bulk convert, 3 weight tensors in one launch ----------------
__global__ void k_cvt3(const float* __restrict__ s0, const float* __restrict__ s1,
                       const float* __restrict__ s2, unsigned short* __restrict__ d0,
                       unsigned short* __restrict__ d1, unsigned short* __restrict__ d2) {
    const float* s = (blockIdx.y == 0) ? s0 : (blockIdx.y == 1) ? s1 : s2;
    unsigned short* d = (blockIdx.y == 0) ? d0 : (blockIdx.y == 1) ? d1 : d2;
    size_t i = ((size_t)blockIdx.x * 256 + threadIdx.x) * 8;
    float4 a = *(const float4*)(s + i);
    float4 b = *(const float4*)(s + i + 4);
    union { unsigned short us[8]; uint4 v; } o;
    o.us[0] = f2bf(a.x); o.us[1] = f2bf(a.y); o.us[2] = f2bf(a.z); o.us[3] = f2bf(a.w);
    o.us[4] = f2bf(b.x); o.us[5] = f2bf(b.y); o.us[6] = f2bf(b.z); o.us[7] = f2bf(b.w);
    *(uint4*)(d + i) = o.v;
}

// ---------------- router (also emits xb = bf16(x)) ----------------
__global__ __launch_bounds__(256) void k_router(
    const float* __restrict__ x, const float* __restrict__ gw,
    int* __restrict__ g_cnt, float* __restrict__ g_prob, float* __restrict__ g_z,
    int* __restrict__ btok, float* __restrict__ bw, unsigned short* __restrict__ xb)
{
    __shared__ float sGw[NEXP * HID];
    __shared__ float sProb[NEXP];
    __shared__ int   sCnt[NEXP];
    __shared__ float sZ;
    __shared__ int   sBase[NEXP];
    __shared__ int   rE0[64], rP0[64], rE1[64], rP1[64];
    __shared__ float rW0[64], rW1[64];

    int tid = threadIdx.x;
    for (int i = tid; i < NEXP * HID; i += 256) sGw[i] = gw[i];
    if (tid < NEXP) { sProb[tid] = 0.f; sCnt[tid] = 0; }
    if (tid == 0) sZ = 0.f;
    __syncthreads();

    int wave = tid >> 6, lane = tid & 63;
    for (int ti = 0; ti < 16; ++ti) {
        int lt = wave * 16 + ti;
        int t = blockIdx.x * 64 + lt;
        const float* xr = x + (size_t)t * HID;
        float acc[NEXP];
        #pragma unroll
        for (int e = 0; e < NEXP; ++e) acc[e] = 0.f;
        for (int k = lane; k < HID; k += 64) {
            float xv = xr[k];
            xb[(size_t)t * HID + k] = f2bf(xv);
            #pragma unroll
            for (int e = 0; e < NEXP; ++e) acc[e] += xv * sGw[e * HID + k];
        }
        #pragma unroll
        for (int e = 0; e < NEXP; ++e) {
            #pragma unroll
            for (int off = 32; off > 0; off >>= 1)
                acc[e] += __shfl_xor(acc[e], off);
        }
        if (lane == 0) {
            float m = acc[0];
            #pragma unroll
            for (int e = 1; e < NEXP; ++e) m = fmaxf(m, acc[e]);
            float s = 0.f;
            float p[NEXP];
            #pragma unroll
            for (int e = 0; e < NEXP; ++e) { p[e] = __expf(acc[e] - m); s += p[e]; }
            float inv = 1.f / s;
            float v1 = -1e30f, v2 = -1e30f; int i1 = -1, i2 = -1;
            #pragma unroll
            for (int e = 0; e < NEXP; ++e) {
                float v = acc[e];
                if (v > v1) { v2 = v1; i2 = i1; v1 = v; i1 = e; }
                else if (v > v2) { v2 = v; i2 = e; }
            }
            float e1v = __expf(v1 - m), e2v = __expf(v2 - m);
            float w0 = e1v / (e1v + e2v), w1 = e2v / (e1v + e2v);
            float lse = m + __logf(s);
            #pragma unroll
            for (int e = 0; e < NEXP; ++e) atomicAdd(&sProb[e], p[e] * inv);
            atomicAdd(&sZ, lse * lse);
            int p0 = atomicAdd(&sCnt[i1], 1);
            int p1 = atomicAdd(&sCnt[i2], 1);
            rE0[lt] = i1; rP0[lt] = p0; rE1[lt] = i2; rP1[lt] = p1;
            rW0[lt] = w0; rW1[lt] = w1;
        }
    }
    __syncthreads();
    if (tid < NEXP) {
        sBase[tid] = atomicAdd(&g_cnt[tid], sCnt[tid]);
        atomicAdd(&g_prob[tid], sProb[tid]);
    }
    if (tid == 64) atomicAdd(g_z, sZ);
    __syncthreads();
    if (tid < 64) {
        int t = blockIdx.x * 64 + tid;
        int e0 = rE0[tid], e1 = rE1[tid];
        int gp0 = sBase[e0] + rP0[tid];
        int gp1 = sBase[e1] + rP1[tid];
        btok[e0 * NUM_TOK + gp0] = t;
        btok[e1 * NUM_TOK + gp1] = t;
        bw[e0 * NUM_TOK + gp0] = rW0[tid];
        bw[e1 * NUM_TOK + gp1] = rW1[tid];
    }
}

// ---------------- finalize: offsets + losses ----------------
__global__ void k_finalize(const int* __restrict__ g_cnt, const float* __restrict__ g_prob,
                           const float* __restrict__ g_z, int* __restrict__ offs,
                           float* __restrict__ out_tail)
{
    if (threadIdx.x == 0) {
        int o = 0; float lb = 0.f;
        for (int e = 0; e < NEXP; ++e) {
            offs[e] = o; o += g_cnt[e];
            lb += (float)g_cnt[e] * g_prob[e];
        }
        offs[NEXP] = o;
        out_tail[0] = (float)NEXP * lb / ((float)NUM_TOK * (float)NUM_TOK) * 0.01f;
        out_tail[1] = (g_z[0] / (float)NUM_TOK) * 0.001f;
    }
}

// ---------------- ffn1: [gate|up] GEMM + SiLU -> h (bf16), double-buffered ----------------
// BK=32 (64 B rows, XOR-4 16 B-chunk swizzle on global src side; LDS side fixed
// by global_load_lds wave-uniform+lane*16 layout).
__global__ __launch_bounds__(256, 4) void k_ffn1(
    const unsigned short* __restrict__ xb, const unsigned short* __restrict__ wgb,
    const unsigned short* __restrict__ wub, unsigned short* __restrict__ h,
    const int* __restrict__ btok, const int* __restrict__ cnt, const int* __restrict__ offs)
{
    int e = blockIdx.x >> 6;
    int mBase = (blockIdx.x & 63) * BM;
    int ne = cnt[e];
    if (mBase >= ne) return;
    int valid = ne - mBase; if (valid > BM) valid = BM;
    int nBase = blockIdx.y * 64;
    int slotBase = offs[e] + mBase;

    __shared__ alignas(16) unsigned short lA[2 * BUFE];   // 16 KB
    __shared__ alignas(16) unsigned short lB[2 * BUFE];   // 16 KB

    int tid = threadIdx.x;
    int w = tid >> 6, lane = tid & 63;
    int lr = lane >> 2;                 // 0..15: row within 16-row group
    int q  = (lane & 3) ^ (lr & 3);     // swizzled 16B chunk (of 4)

    // A staging: wave w covers rows [w*32, w*32+32): 2 instrs x 16 rows
    const unsigned short* aSrc[2];
    unsigned short* aDst[2];
    #pragma unroll
    for (int t = 0; t < 2; ++t) {
        int r = w * 32 + t * 16 + lr;
        int row = mBase + r; if (row > ne - 1) row = ne - 1;
        int tok = btok[e * NUM_TOK + row];
        aSrc[t] = xb + (size_t)tok * HID + q * 8;
        aDst[t] = lA + (w * 32 + t * 16) * BK;
    }
    // B staging: LDS row rb -> j=(rb>>5)*16+(rb&15), is_up=(rb>>4)&1
    const unsigned short* bSrc[2];
    unsigned short* bDst[2];
    #pragma unroll
    for (int t = 0; t < 2; ++t) {
        int rb = w * 32 + t * 16 + lr;
        int j = (rb >> 5) * 16 + (rb & 15);
        const unsigned short* wsrc = ((rb >> 4) & 1) ? wub : wgb;
        bSrc[t] = wsrc + ((size_t)e * INT_DIM + nBase + j) * HID + q * 8;
        bDst[t] = lB + (w * 32 + t * 16) * BK;
    }

    int mOff = (w & 1) * 64, nOff = (w >> 1) * 64;
    int quad = lane >> 4, l16 = lane & 15;

    f32x4 acc[4][4] = {};

    // prologue: tile 0 -> buffer 0
    #pragma unroll
    for (int t = 0; t < 2; ++t) { gl_lds16(aSrc[t], aDst[t]); gl_lds16(bSrc[t], bDst[t]); }

    int buf = 0;
    for (int k0 = 0; k0 < HID; k0 += BK) {
        __syncthreads();   // tile-k loads (issued last iter / prologue) complete
        if (k0 + BK < HID) {
            int nb = (buf ^ 1) * BUFE;
            #pragma unroll
            for (int t = 0; t < 2; ++t) {
                gl_lds16(aSrc[t] + k0 + BK, aDst[t] + nb);
                gl_lds16(bSrc[t] + k0 + BK, bDst[t] + nb);
            }
        }
        const unsigned short* la = lA + buf * BUFE;
        const unsigned short* lb = lB + buf * BUFE;
        bf16x8 af[4], bfr[4];
        #pragma unroll
        for (int mi = 0; mi < 4; ++mi) {
            int r = mOff + mi * 16 + l16;
            af[mi] = *(const bf16x8*)(la + r * BK + ((quad ^ (r & 3)) * 8));
        }
        #pragma unroll
        for (int ni = 0; ni < 4; ++ni) {
            int r = nOff + ni * 16 + l16;
            bfr[ni] = *(const bf16x8*)(lb + r * BK + ((quad ^ (r & 3)) * 8));
        }
        #pragma unroll
        for (int mi = 0; mi < 4; ++mi)
            #pragma unroll
            for (int ni = 0; ni < 4; ++ni)
                acc[mi][ni] = __builtin_amdgcn_mfma_f32_16x16x32_bf16(af[mi], bfr[ni], acc[mi][ni], 0, 0, 0);
        buf ^= 1;
    }

    // epilogue: ni even = gate, ni odd = up at j = nOff/2 + (ni>>1)*16 + l16
    #pragma unroll
    for (int mi = 0; mi < 4; ++mi) {
        #pragma unroll
        for (int rr = 0; rr < 4; ++rr) {
            int row = mOff + mi * 16 + quad * 4 + rr;
            if (row < valid) {
                size_t base = (size_t)(slotBase + row) * INT_DIM + nBase;
                #pragma unroll
                for (int p = 0; p < 2; ++p) {
                    float g = acc[mi][2 * p][rr];
                    float u = acc[mi][2 * p + 1][rr];
                    float hv = (g / (1.f + __expf(-g))) * u;
                    h[base + (nOff >> 1) + p * 16 + l16] = f2bf(hv);
                }
            }
        }
    }
}

// ---------------- ffn2: h @ w_down^T, fused weighted combine, double-buffered ----------------
__global__ __launch_bounds__(256, 4) void k_ffn2(
    const unsigned short* __restrict__ h, const unsigned short* __restrict__ wdb,
    float* __restrict__ out,
    const int* __restrict__ btok, const float* __restrict__ bw,
    const int* __restrict__ cnt, const int* __restrict__ offs)
{
    int e = blockIdx.x >> 6;
    int mBase = (blockIdx.x & 63) * BM;
    int ne = cnt[e];
    if (mBase >= ne) return;
    int valid = ne - mBase; if (valid > BM) valid = BM;
    int nBase = blockIdx.y * 128;
    int slotBase = offs[e] + mBase;

    __shared__ alignas(16) unsigned short lA[2 * BUFE];
    __shared__ alignas(16) unsigned short lB[2 * BUFE];

    int tid = threadIdx.x;
    int w = tid >> 6, lane = tid & 63;
    int lr = lane >> 2;
    int q  = (lane & 3) ^ (lr & 3);

    const unsigned short* aSrc[2];
    unsigned short* aDst[2];
    #pragma unroll
    for (int t = 0; t < 2; ++t) {
        int r = w * 32 + t * 16 + lr;
        int row = (r < valid) ? r : (valid - 1);
        aSrc[t] = h + (size_t)(slotBase + row) * INT_DIM + q * 8;
        aDst[t] = lA + (w * 32 + t * 16) * BK;
    }
    const unsigned short* bSrc[2];
    unsigned short* bDst[2];
    #pragma unroll
    for (int t = 0; t < 2; ++t) {
        int rb = w * 32 + t * 16 + lr;
        bSrc[t] = wdb + ((size_t)e * HID + nBase + rb) * INT_DIM + q * 8;
        bDst[t] = lB + (w * 32 + t * 16) * BK;
    }

    int mOff = (w & 1) * 64, nOff = (w >> 1) * 64;
    int quad = lane >> 4, l16 = lane & 15;

    f32x4 acc[4][4] = {};

    #pragma unroll
    for (int t = 0; t < 2; ++t) { gl_lds16(aSrc[t], aDst[t]); gl_lds16(bSrc[t], bDst[t]); }

    int buf = 0;
    for (int k0 = 0; k0 < INT_DIM; k0 += BK) {
        __syncthreads();
        if (k0 + BK < INT_DIM) {
            int nb = (buf ^ 1) * BUFE;
            #pragma unroll
            for (int t = 0; t < 2; ++t) {
                gl_lds16(aSrc[t] + k0 + BK, aDst[t] + nb);
                gl_lds16(bSrc[t] + k0 + BK, bDst[t] + nb);
            }
        }
        const unsigned short* la = lA + buf * BUFE;
        const unsigned short* lb = lB + buf * BUFE;
        bf16x8 af[4], bfr[4];
        #pragma unroll
        for (int mi = 0; mi < 4; ++mi) {
            int r = mOff + mi * 16 + l16;
            af[mi] = *(const bf16x8*)(la + r * BK + ((quad ^ (r & 3)) * 8));
        }
        #pragma unroll
        for (int ni = 0; ni < 4; ++ni) {
            int r = nOff + ni * 16 + l16;
            bfr[ni] = *(const bf16x8*)(lb + r * BK + ((quad ^ (r & 3)) * 8));
        }
        #pragma unroll
        for (int mi = 0; mi < 4; ++mi)
            #pragma unroll
            for (int ni = 0; ni < 4; ++ni)
                acc[mi][ni] = __builtin_amdgcn_mfma_f32_16x16x32_bf16(af[mi], bfr[ni], acc[mi][ni], 0, 0, 0);
        buf ^= 1;
    }

    // epilogue: out[tok] += w_slot * y  (exactly 2 commutative fp32 adds per element)
    #pragma unroll
    for (int mi = 0; mi < 4; ++mi) {
        #pragma unroll
        for (int rr = 0; rr < 4; ++rr) {
            int row = mOff + mi * 16 + quad * 4 + rr;
            if (row < valid) {
                int tok = btok[e * NUM_TOK + mBase + row];
                float wgt = bw[e * NUM_TOK + mBase + row];
                float* obase = out + (size_t)tok * HID + nBase + nOff;
                #pragma unroll
                for (int ni = 0; ni < 4; ++ni)
                    atomicAdd(obase + ni * 16 + l16, wgt * acc[mi][ni][rr]);
            }
        }
    }
}

extern "C" void kernel_launch(void* const* d_in, const int* in_sizes, int n_in,
                              void* d_out, int out_size, void* d_ws, size_t ws_size,
                              hipStream_t stream) {
    const float* x  = (const float*)d_in[0];
    const float* gw = (const float*)d_in[1];
    const float* wg = (const float*)d_in[2];
    const float* wu = (const float*)d_in[3];
    const float* wd = (const float*)d_in[4];
    float* out = (float*)d_out;

    char* p = (char*)d_ws;
    unsigned short* xb  = (unsigned short*)p; p += (size_t)NUM_TOK * HID * 2;        // 16 MB
    unsigned short* h   = (unsigned short*)p; p += (size_t)NSLOT * INT_DIM * 2;      // 128 MB
    unsigned short* wgb = (unsigned short*)p; p += (size_t)NEXP * INT_DIM * HID * 2; // 64 MB
    unsigned short* wub = (unsigned short*)p; p += (size_t)NEXP * INT_DIM * HID * 2; // 64 MB
    unsigned short* wdb = (unsigned short*)p; p += (size_t)NEXP * HID * INT_DIM * 2; // 64 MB
    int* btok           = (int*)p;            p += (size_t)NEXP * NUM_TOK * 4;       // 256 KB
    float* bw           = (float*)p;          p += (size_t)NEXP * NUM_TOK * 4;       // 256 KB
    int* cnt            = (int*)p;            p += 32;
    float* probSum      = (float*)p;          p += 32;
    float* zSum         = (float*)p;          p += 16;
    int* offs           = (int*)p;            p += 64;

    hipMemsetAsync(cnt, 0, 80, stream);
    hipMemsetAsync(out, 0, (size_t)NUM_TOK * HID * sizeof(float), stream);

    k_cvt3<<<dim3(16384, 3), 256, 0, stream>>>(wg, wu, wd, wgb, wub, wdb);
    k_router<<<128, 256, 0, stream>>>(x, gw, cnt, probSum, zSum, btok, bw, xb);
    k_finalize<<<1, 64, 0, stream>>>(cnt, probSum, zSum, offs, out + (size_t)NUM_TOK * HID);
    k_ffn1<<<dim3(512, 64), 256, 0, stream>>>(xb, wgb, wub, h, btok, cnt, offs);
    k_ffn2<<<dim3(512, 8), 256, 0, stream>>>(h, wdb, out, btok, bw, cnt, offs);
}